// Round 7
// baseline (666.664 us; speedup 1.0000x reference)
//
#include <hip/hip_runtime.h>
#include <stdint.h>

// ============================================================================
// RelativeSelfAttention on MI355X (gfx950)
// B=32, C=256, S=4096, heads=32, "HEAD_DIM"=512, L=128
// per (b,h): Q/K/V = qkv[b, g*512+h*16 .. +16, :] viewed as [d=512][l=128],
//   d = c16*32 + s_hi, s = s_hi*128 + l.
// Output reshape: Ot[s2][D], D = h*16 + (d>>5), s2 = (d&31)*128 + l.
// R7: k_qkv_gemm v3 — 256x128 tile / 8 waves (half the Xt refetch, 2x MFMA
//     density) + fused head-axis sum-of-squares (LDS-reduced, one coalesced
//     atomicAdd pass) -> k_scales deleted; tiny k_ss2scale converts in place.
// ============================================================================

typedef float     f32x4   __attribute__((ext_vector_type(4)));
typedef short     bf16x8  __attribute__((ext_vector_type(8)));
typedef float     floatx4 __attribute__((ext_vector_type(4)));
typedef uint16_t  ushortx8 __attribute__((ext_vector_type(8)));
typedef uint16_t  ushortx4 __attribute__((ext_vector_type(4)));

#define DEVI static __device__ __forceinline__

DEVI float bf2f(uint16_t u) { union { uint32_t i; float f; } x; x.i = ((uint32_t)u) << 16; return x.f; }
DEVI uint16_t f2bf(float f) {
  union { float f; uint32_t i; } x; x.f = f;
  uint32_t r = x.i + 0x7fff + ((x.i >> 16) & 1);
  return (uint16_t)(r >> 16);
}

DEVI void gload16(const void* g, void* l) {
  __builtin_amdgcn_global_load_lds((const __attribute__((address_space(1))) void*)g,
                                   (__attribute__((address_space(3))) void*)l, 16, 0, 0);
}

DEVI float redmax16(float v) {
  v = fmaxf(v, __shfl_xor(v, 1)); v = fmaxf(v, __shfl_xor(v, 2));
  v = fmaxf(v, __shfl_xor(v, 4)); v = fmaxf(v, __shfl_xor(v, 8));
  return v;
}
DEVI float redsum16(float v) {
  v += __shfl_xor(v, 1); v += __shfl_xor(v, 2);
  v += __shfl_xor(v, 4); v += __shfl_xor(v, 8);
  return v;
}

// ---------------------------------------------------------------------------
// X[b][c][s] f32  ->  Xt[b][s][c] bf16   (LDS 64x64 padded transpose)
// grid (st=64, ct=4, NB)
// ---------------------------------------------------------------------------
__global__ __launch_bounds__(256) void k_transpose_x(const float* __restrict__ X,
                                                     uint16_t* __restrict__ Xt) {
  __shared__ float tile[64][65];
  int t = threadIdx.x;
  int st = blockIdx.x, ct = blockIdx.y, b = blockIdx.z;
  int row = t >> 2, cq = t & 3;
  const float* src = X + ((size_t)(b * 256 + ct * 64 + row)) * 4096 + st * 64 + cq * 16;
#pragma unroll
  for (int k = 0; k < 4; ++k) {
    floatx4 v = *(const floatx4*)(src + k * 4);
    tile[row][cq * 16 + k * 4 + 0] = v[0];
    tile[row][cq * 16 + k * 4 + 1] = v[1];
    tile[row][cq * 16 + k * 4 + 2] = v[2];
    tile[row][cq * 16 + k * 4 + 3] = v[3];
  }
  __syncthreads();
  int srow = t >> 2, oq = t & 3;
  ushortx8 o0, o1;
#pragma unroll
  for (int k = 0; k < 8; ++k) o0[k] = f2bf(tile[oq * 16 + k][srow]);
#pragma unroll
  for (int k = 0; k < 8; ++k) o1[k] = f2bf(tile[oq * 16 + 8 + k][srow]);
  uint16_t* dst = Xt + ((size_t)(b * 4096 + st * 64 + srow)) * 256 + ct * 64 + oq * 16;
  *(ushortx8*)dst = o0;
  *(ushortx8*)(dst + 8) = o1;
}

// ---------------------------------------------------------------------------
// flat f32 -> bf16 (weights)
// ---------------------------------------------------------------------------
__global__ __launch_bounds__(256) void k_cvt_bf16(const float* __restrict__ src,
                                                  uint16_t* __restrict__ dst, int n) {
  int i = (blockIdx.x * 256 + threadIdx.x) * 4;
  if (i >= n) return;
  floatx4 v = *(const floatx4*)(src + i);
  ushortx4 o;
  o[0] = f2bf(v[0]); o[1] = f2bf(v[1]); o[2] = f2bf(v[2]); o[3] = f2bf(v[3]);
  *(ushortx4*)(dst + i) = o;
}

// ---------------------------------------------------------------------------
// qkv[b][o][s] = sum_c W[o][c]*Xt[b][s][c] + bias[o]   (bf16 out)
// 256x128 tile, 8 waves (wr=wave>>1 in 0..3, wc=wave&1), BK=64.
// Fused: block-local sum-of-squares over its 16 heads (for q/k blocks),
//   one coalesced atomicAdd pass into gss[b][g][c16][4096] (f32, pre-zeroed).
// grid (ot=6, st=32, NB)
// ---------------------------------------------------------------------------
__global__ __launch_bounds__(512) void k_qkv_gemm(const uint16_t* __restrict__ W,
                                                  const uint16_t* __restrict__ Xt,
                                                  const float* __restrict__ bias_g,
                                                  uint16_t* __restrict__ qkv,
                                                  float* __restrict__ gss) {
  __shared__ __align__(16) union {
    struct { uint16_t A[256 * 64]; uint16_t B[128 * 64]; } s;   // staging 49152 B
    struct { uint16_t c[128 * 136]; float ssl[16 * 128]; } e;   // epilogue 43008 B
  } sm;
  uint16_t* As = sm.s.A;
  uint16_t* Bs = sm.s.B;
  int t = threadIdx.x, lane = t & 63, wave = t >> 6;
  int ot = blockIdx.x, st = blockIdx.y, b = blockIdx.z;
  int wr = wave >> 1, wc = wave & 1;
  f32x4 acc[4][4] = {};
  int srow = lane >> 3;
  int sc_us = ((((lane & 7) * 16) ^ ((srow & 7) << 4)) >> 1);
  const uint16_t* Ag = W + (size_t)(ot * 256 + wave * 8 + srow) * 256;
  const uint16_t* Bg = Xt + ((size_t)(b * 4096 + st * 128 + wave * 8 + srow)) * 256;

  for (int kc = 0; kc < 4; ++kc) {
    __syncthreads();
#pragma unroll
    for (int c = 0; c < 4; ++c)
      gload16(Ag + (size_t)(c * 64) * 256 + kc * 64 + sc_us, &As[(c * 64 + wave * 8) * 64]);
#pragma unroll
    for (int c = 0; c < 2; ++c)
      gload16(Bg + (size_t)(c * 64) * 256 + kc * 64 + sc_us, &Bs[(c * 64 + wave * 8) * 64]);
    __syncthreads();
#pragma unroll
    for (int kk = 0; kk < 2; ++kk) {
      bf16x8 a[4], bw[4];
#pragma unroll
      for (int i = 0; i < 4; ++i) {
        int r = wr * 64 + i * 16 + (lane & 15);
        a[i] = *(const bf16x8*)&As[r * 64 + ((kk * 32 + (lane >> 4) * 8) ^ ((r & 7) << 3))];
      }
#pragma unroll
      for (int j = 0; j < 4; ++j) {
        int r = wc * 64 + j * 16 + (lane & 15);
        bw[j] = *(const bf16x8*)&Bs[r * 64 + ((kk * 32 + (lane >> 4) * 8) ^ ((r & 7) << 3))];
      }
#pragma unroll
      for (int i = 0; i < 4; ++i)
#pragma unroll
        for (int j = 0; j < 4; ++j)
          acc[i][j] = __builtin_amdgcn_mfma_f32_16x16x32_bf16(a[i], bw[j], acc[i][j], 0, 0, 0);
    }
  }

  // ---- epilogue ----
  int o0 = ot * 256 + wr * 64;
  float bv[4][4];
#pragma unroll
  for (int i = 0; i < 4; ++i)
#pragma unroll
    for (int r = 0; r < 4; ++r) bv[i][r] = bias_g[o0 + i * 16 + (lane >> 4) * 4 + r];
  bool isqk = (ot < 4);
  __syncthreads();                      // staging reads complete
#pragma unroll
  for (int k = 0; k < 4; ++k) sm.e.ssl[k * 512 + t] = 0.f;
  __syncthreads();
  if (isqk) {
#pragma unroll
    for (int j = 0; j < 4; ++j)
#pragma unroll
      for (int r = 0; r < 4; ++r) {
        float ssv = 0.f;
#pragma unroll
        for (int i = 0; i < 4; ++i) {
          float v = acc[i][j][r] + bv[i][r];
          ssv += v * v;
        }
        int c16 = (lane >> 4) * 4 + r;
        int scol = wc * 64 + j * 16 + (lane & 15);
        atomicAdd(&sm.e.ssl[c16 * 128 + scol], ssv);
      }
  }
  __syncthreads();
  // C-store in two 128-row halves through LDS repack
#pragma unroll
  for (int h2 = 0; h2 < 2; ++h2) {
    if ((wr >> 1) == h2) {
      int lr0 = (wr & 1) * 64;
#pragma unroll
      for (int i = 0; i < 4; ++i)
#pragma unroll
        for (int j = 0; j < 4; ++j)
#pragma unroll
          for (int r = 0; r < 4; ++r) {
            int lrow = lr0 + i * 16 + (lane >> 4) * 4 + r;
            int scol = wc * 64 + j * 16 + (lane & 15);
            sm.e.c[lrow * 136 + scol] = f2bf(acc[i][j][r] + bv[i][r]);
          }
    }
    __syncthreads();
    uint16_t* outb = qkv + ((size_t)b * 1536 + ot * 256 + h2 * 128) * 4096 + st * 128;
    int rrow = t >> 4, rcol = (t & 15) * 8;
#pragma unroll
    for (int p = 0; p < 4; ++p) {
      int row = p * 32 + rrow;
      ushortx8 v = *(ushortx8*)&sm.e.c[row * 136 + rcol];
      *(ushortx8*)(outb + (size_t)row * 4096 + rcol) = v;
    }
    __syncthreads();
  }
  // global ss accumulation (coalesced, 4 passes)
  if (isqk) {
    int g = ot >> 1;
    float* gb = gss + (size_t)b * 131072 + g * 65536 + st * 128;
#pragma unroll
    for (int it = 0; it < 4; ++it) {
      int idx = it * 512 + t;
      int c16 = idx >> 7, scol = idx & 127;
      atomicAdd(&gb[(size_t)c16 * 4096 + scol], sm.e.ssl[c16 * 128 + scol]);
    }
  }
}

// ---------------------------------------------------------------------------
// gss -> scale = 1/max(sqrt(ss), eps), in place
// ---------------------------------------------------------------------------
__global__ __launch_bounds__(256) void k_ss2scale(float* __restrict__ gss, int n) {
  int i = (blockIdx.x * 256 + threadIdx.x) * 4;
  if (i >= n) return;
  floatx4 v = *(const floatx4*)(gss + i);
#pragma unroll
  for (int j = 0; j < 4; ++j) v[j] = 1.0f / fmaxf(sqrtf(v[j]), 1e-12f);
  *(floatx4*)(gss + i) = v;
}

// ---------------------------------------------------------------------------
// k_attn v3: per (b,h), 512 threads / 8 waves, 52.5KB LDS.
//  QK^T: BK=32 (kc=c16 0..15), fused-scale register staging into pad-40 rows.
//  softmax in-register (16-lane groups), unnormalized P -> Pb (XOR-swz).
//  PV: V [256][32] per (mc,half) via gload16; epilogue via pad-66 patches,
//      coalesced stores into OtT[D][s2] (aliases qkv q-region).
// grid (h=32, NB)
// ---------------------------------------------------------------------------
__global__ __launch_bounds__(512, 4) void k_attn(const uint16_t* __restrict__ qkv,
                                                 const float* __restrict__ scaleB,
                                                 uint16_t* OtAll) {
  __shared__ __align__(16) uint16_t stage[10240]; // QT[128][40]+KT[128][40]; V[256][32]; epi patches
  __shared__ __align__(16) uint16_t Pb[16384];    // P [128][128] (XOR-swizzled)
  __shared__ float rsum[128];
  int t = threadIdx.x, lane = t & 63, w = t >> 6;
  int h = blockIdx.x, b = blockIdx.y;
  const uint16_t* qg = qkv + ((size_t)(b * 1536) + h * 16) * 4096;
  const uint16_t* kg = qkv + ((size_t)(b * 1536) + 512 + h * 16) * 4096;
  const float* sq = scaleB + (size_t)b * 131072;
  const float* sk = sq + 65536;
  uint16_t* QT = stage;          // [128][40]
  uint16_t* KT = stage + 5120;   // [128][40]

  int sl = t & 127;   // l
  int sb8 = t >> 7;   // dd-octet 0..3

  // ---- S = Q^ * K^T (K=512 in 16 chunks of 32), fused scaling ----
  f32x4 accs[8] = {};
  for (int kc = 0; kc < 16; ++kc) {
    const uint16_t* qrow = qg + (size_t)kc * 4096 + sl;
    const uint16_t* krow = kg + (size_t)kc * 4096 + sl;
    const float* sqr = sq + kc * 4096 + sl;
    const float* skr = sk + kc * 4096 + sl;
    ushortx8 oq, ok;
#pragma unroll
    for (int j = 0; j < 8; ++j) {
      int soff = (sb8 * 8 + j) * 128;
      oq[j] = f2bf(bf2f(qrow[soff]) * sqr[soff]);
      ok[j] = f2bf(bf2f(krow[soff]) * skr[soff]);
    }
    __syncthreads();  // previous MFMA reads done
    int lidx = sl * 40 + sb8 * 8;
    *(ushortx8*)&QT[lidx] = oq;
    *(ushortx8*)&KT[lidx] = ok;
    __syncthreads();
    int ra = w * 16 + (lane & 15);
    bf16x8 aq = *(const bf16x8*)&QT[ra * 40 + (lane >> 4) * 8];
#pragma unroll
    for (int mf = 0; mf < 8; ++mf) {
      int rm = mf * 16 + (lane & 15);
      bf16x8 bk = *(const bf16x8*)&KT[rm * 40 + (lane >> 4) * 8];
      accs[mf] = __builtin_amdgcn_mfma_f32_16x16x32_bf16(aq, bk, accs[mf], 0, 0, 0);
    }
  }

  // ---- softmax (row spread over 16-lane group), P unnormalized ----
#pragma unroll
  for (int r = 0; r < 4; ++r) {
    float mx = accs[0][r];
#pragma unroll
    for (int mf = 1; mf < 8; ++mf) mx = fmaxf(mx, accs[mf][r]);
    mx = redmax16(mx);
    float sum = 0.f;
#pragma unroll
    for (int mf = 0; mf < 8; ++mf) {
      float e = __expf(accs[mf][r] - mx);
      accs[mf][r] = e;
      sum += e;
    }
    sum = redsum16(sum);
    int l = w * 16 + (lane >> 4) * 4 + r;
    if ((lane & 15) == 0) rsum[l] = 1.0f / sum;
#pragma unroll
    for (int mf = 0; mf < 8; ++mf) {
      int m = mf * 16 + (lane & 15);
      Pb[l * 128 + (m ^ ((l & 7) << 3))] = f2bf(accs[mf][r]);
    }
  }
  __syncthreads();

  // ---- out = V * P^T ----
  const uint16_t* vg = qkv + ((size_t)(b * 1536) + 1024 + h * 16) * 4096;
  uint16_t* OtT = OtAll + (size_t)b * 6291456;  // [512][4096] q-region of batch b
  uint16_t* Vt = stage;                          // [256][32]
  int vrow = lane >> 2;
  int vcol_us = ((((lane & 3) * 16) ^ ((vrow & 3) << 4)) >> 1);

#pragma unroll
  for (int lc = 0; lc < 2; ++lc) {
    f32x4 acco[2][2][4] = {};
    for (int mc = 0; mc < 4; ++mc) {
      bf16x8 bp[4];
#pragma unroll
      for (int lf = 0; lf < 4; ++lf) {
        int l = lc * 64 + lf * 16 + (lane & 15);
        bp[lf] = *(const bf16x8*)&Pb[l * 128 + ((mc * 32 + (lane >> 4) * 8) ^ ((l & 7) << 3))];
      }
#pragma unroll
      for (int half = 0; half < 2; ++half) {
        __syncthreads();
#pragma unroll
        for (int c = 0; c < 2; ++c) {
          int d = half * 256 + w * 32 + c * 16 + vrow;
          gload16(vg + (size_t)(d >> 5) * 4096 + (d & 31) * 128 + mc * 32 + vcol_us,
                  &Vt[(w * 32 + c * 16) * 32]);
        }
        __syncthreads();
#pragma unroll
        for (int df = 0; df < 2; ++df) {
          int rv = w * 32 + df * 16 + (lane & 15);
          bf16x8 av = *(const bf16x8*)&Vt[rv * 32 + (((lane >> 4) * 8) ^ ((rv & 3) << 3))];
#pragma unroll
          for (int lf = 0; lf < 4; ++lf)
            acco[half][df][lf] =
                __builtin_amdgcn_mfma_f32_16x16x32_bf16(av, bp[lf], acco[half][df][lf], 0, 0, 0);
        }
      }
    }
    float scl[4];
#pragma unroll
    for (int lf = 0; lf < 4; ++lf) scl[lf] = rsum[lc * 64 + lf * 16 + (lane & 15)];

    __syncthreads();  // all MFMA reads of Vt done; stage region free for patches
    uint16_t* patch = stage + w * 1056;  // [16][66] per wave
#pragma unroll
    for (int half = 0; half < 2; ++half) {
      uint16_t* obase = OtT + (size_t)(h * 16 + half * 8 + w) * 4096;
#pragma unroll
      for (int df = 0; df < 2; ++df) {
#pragma unroll
        for (int r = 0; r < 4; ++r) {
          int dlocal = (lane >> 4) * 4 + r;
#pragma unroll
          for (int lf = 0; lf < 4; ++lf)
            patch[dlocal * 66 + lf * 16 + (lane & 15)] = f2bf(acco[half][df][lf][r] * scl[lf]);
        }
        asm volatile("s_waitcnt lgkmcnt(0)" ::: "memory");
        __builtin_amdgcn_sched_barrier(0);
        int dl = lane >> 2, l8 = (lane & 3) * 16;
        uint16_t tmp[16];
#pragma unroll
        for (int e = 0; e < 8; ++e)
          *(uint32_t*)&tmp[e * 2] = *(const uint32_t*)&patch[dl * 66 + l8 + e * 2];
        uint16_t* gp = obase + (df * 16 + dl) * 128 + lc * 64 + l8;
        *(ushortx8*)gp = *(ushortx8*)&tmp[0];
        *(ushortx8*)(gp + 8) = *(ushortx8*)&tmp[8];
        asm volatile("s_waitcnt lgkmcnt(0)" ::: "memory");  // patch reads done before next overwrite
        __builtin_amdgcn_sched_barrier(0);
      }
    }
  }
}

// ---------------------------------------------------------------------------
// final[b][c][s] = sum_D Wp[c][D]*OtT[D][s] + bias[c]   (f32 out)
// B staged by 8-element gather from OtT (stride 4096); grid (st=32, ct=2, NB)
// ---------------------------------------------------------------------------
__global__ __launch_bounds__(256) void k_proj_gemm(const uint16_t* __restrict__ Wp,
                                                   const uint16_t* __restrict__ OtAll,
                                                   const float* __restrict__ bias_g,
                                                   float* __restrict__ outp) {
  __shared__ __align__(16) uint16_t As[128 * 64];
  __shared__ __align__(16) uint16_t Bs[128 * 64];
  int t = threadIdx.x, lane = t & 63, wave = t >> 6;
  int st = blockIdx.x, ct = blockIdx.y, b = blockIdx.z;
  int wr = wave >> 1, wc = wave & 1;
  f32x4 acc[4][4] = {};
  int srow = lane >> 3;
  int sc_us = ((((lane & 7) * 16) ^ ((srow & 7) << 4)) >> 1);
  const uint16_t* Ag = Wp + (size_t)(ct * 128 + wave * 8 + srow) * 512;
  const uint16_t* Ob = OtAll + (size_t)b * 6291456;

  for (int kc = 0; kc < 8; ++kc) {
    __syncthreads();
#pragma unroll
    for (int c = 0; c < 4; ++c)
      gload16(Ag + (size_t)(c * 32) * 512 + kc * 64 + sc_us, &As[(c * 32 + wave * 8) * 64]);
#pragma unroll
    for (int k = 0; k < 4; ++k) {
      int cid = k * 256 + t;
      int row = cid & 127, dd8 = cid >> 7;
      const uint16_t* src = Ob + (size_t)(kc * 64 + dd8 * 8) * 4096 + st * 128 + row;
      ushortx8 o;
#pragma unroll
      for (int j = 0; j < 8; ++j) o[j] = src[(size_t)j * 4096];
      *(ushortx8*)&Bs[row * 64 + ((dd8 * 8) ^ ((row & 7) << 3))] = o;
    }
    __syncthreads();
#pragma unroll
    for (int kk = 0; kk < 2; ++kk) {
      bf16x8 a[4], bw[4];
#pragma unroll
      for (int i = 0; i < 4; ++i) {
        int r = wr * 64 + i * 16 + (lane & 15);
        a[i] = *(const bf16x8*)&As[r * 64 + ((kk * 32 + (lane >> 4) * 8) ^ ((r & 7) << 3))];
      }
#pragma unroll
      for (int j = 0; j < 4; ++j) {
        int r = wc * 64 + j * 16 + (lane & 15);
        bw[j] = *(const bf16x8*)&Bs[r * 64 + ((kk * 32 + (lane >> 4) * 8) ^ ((r & 7) << 3))];
      }
#pragma unroll
      for (int i = 0; i < 4; ++i)
#pragma unroll
        for (int j = 0; j < 4; ++j)
          acc[i][j] = __builtin_amdgcn_mfma_f32_16x16x32_bf16(a[i], bw[j], acc[i][j], 0, 0, 0);
    }
  }
  int c0 = ct * 128 + wr * 64, s0 = st * 128 + wc * 64;
  float bv[4][4];
#pragma unroll
  for (int i = 0; i < 4; ++i)
#pragma unroll
    for (int r = 0; r < 4; ++r) bv[i][r] = bias_g[c0 + i * 16 + (lane >> 4) * 4 + r];
#pragma unroll
  for (int i = 0; i < 4; ++i)
#pragma unroll
    for (int j = 0; j < 4; ++j)
#pragma unroll
      for (int r = 0; r < 4; ++r) {
        int c = c0 + i * 16 + (lane >> 4) * 4 + r;
        int s = s0 + j * 16 + (lane & 15);
        outp[((size_t)b * 256 + c) * 4096 + s] = acc[i][j][r] + bv[i][r];
      }
}

// ---------------------------------------------------------------------------
extern "C" void kernel_launch(void* const* d_in, const int* in_sizes, int n_in,
                              void* d_out, int out_size, void* d_ws, size_t ws_size,
                              hipStream_t stream) {
  const float* X      = (const float*)d_in[0];
  const float* qkv_w  = (const float*)d_in[1];
  const float* qkv_b  = (const float*)d_in[2];
  const float* proj_w = (const float*)d_in[3];
  const float* proj_b = (const float*)d_in[4];
  float* outp = (float*)d_out;

  const size_t SZ_XT  = 2097152;   // Xt bf16 [4096][256]
  const size_t SZ_QKV = 12582912;  // qkv; q region doubles as OtT[512][4096]
  const size_t SZ_SC  = 524288;    // gss/scale f32 [2][16][4096]
  const size_t SZ_W   = 786432 + 262144;

  int NB = 0;
  const int cand[6] = {32, 16, 8, 4, 2, 1};
  for (int ci = 0; ci < 6; ++ci) {
    size_t need = SZ_W + (size_t)cand[ci] * (SZ_XT + SZ_QKV + SZ_SC);
    if (need <= ws_size) { NB = cand[ci]; break; }
  }
  if (NB == 0) return;

  char* ws = (char*)d_ws;
  uint16_t* Wqb  = (uint16_t*)(ws);
  uint16_t* Wpb  = (uint16_t*)(ws + 786432);
  char*     gbuf = ws + SZ_W;
  uint16_t* Xt   = (uint16_t*)(gbuf);
  uint16_t* qkvb = (uint16_t*)(gbuf + (size_t)NB * SZ_XT);
  float*    scaleB = (float*)(gbuf + (size_t)NB * (SZ_XT + SZ_QKV)); // per-b stride 131072 f32

  k_cvt_bf16<<<dim3(384), 256, 0, stream>>>(qkv_w, Wqb, 1536 * 256);
  k_cvt_bf16<<<dim3(128), 256, 0, stream>>>(proj_w, Wpb, 256 * 512);

  for (int b0 = 0; b0 < 32; b0 += NB) {
    const float* Xg   = X + (size_t)b0 * 256 * 4096;
    float*       outg = outp + (size_t)b0 * 256 * 4096;
    hipMemsetAsync(scaleB, 0, (size_t)NB * SZ_SC, stream);
    k_transpose_x<<<dim3(64, 4, NB), 256, 0, stream>>>(Xg, Xt);
    k_qkv_gemm<<<dim3(6, 32, NB), 512, 0, stream>>>(Wqb, Xt, qkv_b, qkvb, scaleB);
    k_ss2scale<<<dim3(NB * 128), 256, 0, stream>>>(scaleB, NB * 131072);
    k_attn<<<dim3(32, NB), 512, 0, stream>>>(qkvb, scaleB, qkvb /*OtT*/);
    k_proj_gemm<<<dim3(32, 2, NB), 256, 0, stream>>>(Wpb, qkvb /*OtT*/, proj_b, outg);
  }
}

// Round 8
// 575.495 us; speedup vs baseline: 1.1584x; 1.1584x over previous
//
#include <hip/hip_runtime.h>
#include <stdint.h>

// ============================================================================
// RelativeSelfAttention on MI355X (gfx950)
// B=32, C=256, S=4096, heads=32, "HEAD_DIM"=512, L=128
// per (b,h): Q/K/V = qkv[b, g*512+h*16 .. +16, :] viewed as [d=512][l=128],
//   d = c16*32 + s_hi, s = s_hi*128 + l.
// Output reshape: Ot[s2][D], D = h*16 + (d>>5), s2 = (d&31)*128 + l.
// R8: revert R7's qkv rewrite (epilogue-fused ss regressed 182->330us).
//     k_attn v4 = v3 + T14 software-pipelined QK staging (prefetch kc+1
//     loads before kc MFMA) + T5 setprio around MFMA clusters.
// ============================================================================

typedef float     f32x4   __attribute__((ext_vector_type(4)));
typedef short     bf16x8  __attribute__((ext_vector_type(8)));
typedef float     floatx4 __attribute__((ext_vector_type(4)));
typedef uint16_t  ushortx8 __attribute__((ext_vector_type(8)));
typedef uint16_t  ushortx4 __attribute__((ext_vector_type(4)));

#define DEVI static __device__ __forceinline__

DEVI float bf2f(uint16_t u) { union { uint32_t i; float f; } x; x.i = ((uint32_t)u) << 16; return x.f; }
DEVI uint16_t f2bf(float f) {
  union { float f; uint32_t i; } x; x.f = f;
  uint32_t r = x.i + 0x7fff + ((x.i >> 16) & 1);
  return (uint16_t)(r >> 16);
}

DEVI void gload16(const void* g, void* l) {
  __builtin_amdgcn_global_load_lds((const __attribute__((address_space(1))) void*)g,
                                   (__attribute__((address_space(3))) void*)l, 16, 0, 0);
}

DEVI float redmax16(float v) {
  v = fmaxf(v, __shfl_xor(v, 1)); v = fmaxf(v, __shfl_xor(v, 2));
  v = fmaxf(v, __shfl_xor(v, 4)); v = fmaxf(v, __shfl_xor(v, 8));
  return v;
}
DEVI float redsum16(float v) {
  v += __shfl_xor(v, 1); v += __shfl_xor(v, 2);
  v += __shfl_xor(v, 4); v += __shfl_xor(v, 8);
  return v;
}

// ---------------------------------------------------------------------------
// X[b][c][s] f32  ->  Xt[b][s][c] bf16   (LDS 64x64 padded transpose)
// grid (st=64, ct=4, NB)
// ---------------------------------------------------------------------------
__global__ __launch_bounds__(256) void k_transpose_x(const float* __restrict__ X,
                                                     uint16_t* __restrict__ Xt) {
  __shared__ float tile[64][65];
  int t = threadIdx.x;
  int st = blockIdx.x, ct = blockIdx.y, b = blockIdx.z;
  int row = t >> 2, cq = t & 3;
  const float* src = X + ((size_t)(b * 256 + ct * 64 + row)) * 4096 + st * 64 + cq * 16;
#pragma unroll
  for (int k = 0; k < 4; ++k) {
    floatx4 v = *(const floatx4*)(src + k * 4);
    tile[row][cq * 16 + k * 4 + 0] = v[0];
    tile[row][cq * 16 + k * 4 + 1] = v[1];
    tile[row][cq * 16 + k * 4 + 2] = v[2];
    tile[row][cq * 16 + k * 4 + 3] = v[3];
  }
  __syncthreads();
  int srow = t >> 2, oq = t & 3;
  ushortx8 o0, o1;
#pragma unroll
  for (int k = 0; k < 8; ++k) o0[k] = f2bf(tile[oq * 16 + k][srow]);
#pragma unroll
  for (int k = 0; k < 8; ++k) o1[k] = f2bf(tile[oq * 16 + 8 + k][srow]);
  uint16_t* dst = Xt + ((size_t)(b * 4096 + st * 64 + srow)) * 256 + ct * 64 + oq * 16;
  *(ushortx8*)dst = o0;
  *(ushortx8*)(dst + 8) = o1;
}

// ---------------------------------------------------------------------------
// flat f32 -> bf16 (weights)
// ---------------------------------------------------------------------------
__global__ __launch_bounds__(256) void k_cvt_bf16(const float* __restrict__ src,
                                                  uint16_t* __restrict__ dst, int n) {
  int i = (blockIdx.x * 256 + threadIdx.x) * 4;
  if (i >= n) return;
  floatx4 v = *(const floatx4*)(src + i);
  ushortx4 o;
  o[0] = f2bf(v[0]); o[1] = f2bf(v[1]); o[2] = f2bf(v[2]); o[3] = f2bf(v[3]);
  *(ushortx4*)(dst + i) = o;
}

// ---------------------------------------------------------------------------
// qkv[b][o][s] = sum_c W[o][c]*Xt[b][s][c] + bias[o]   (bf16 out)
// grid (ot=12, st=32, NB); C-write via LDS repack (coalesced 16B/lane)
// ---------------------------------------------------------------------------
__global__ __launch_bounds__(256) void k_qkv_gemm(const uint16_t* __restrict__ W,
                                                  const uint16_t* __restrict__ Xt,
                                                  const float* __restrict__ bias_g,
                                                  uint16_t* __restrict__ qkv) {
  __shared__ __align__(16) union {
    uint16_t ab[2][128 * 64];   // As, Bs
    uint16_t c[128 * 136];      // C repack (padded stride)
  } sm;
  uint16_t* As = sm.ab[0];
  uint16_t* Bs = sm.ab[1];
  int t = threadIdx.x, lane = t & 63, wave = t >> 6;
  int ot = blockIdx.x, st = blockIdx.y, b = blockIdx.z;
  int wr = wave >> 1, wc = wave & 1;
  f32x4 acc[4][4] = {};
  int srow = lane >> 3;
  int sc_us = ((((lane & 7) * 16) ^ ((srow & 7) << 4)) >> 1);
  const uint16_t* Ag = W + (size_t)(ot * 128 + wave * 8 + srow) * 256;
  const uint16_t* Bg = Xt + ((size_t)(b * 4096 + st * 128 + wave * 8 + srow)) * 256;

  for (int kc = 0; kc < 4; ++kc) {
    __syncthreads();
#pragma unroll
    for (int c = 0; c < 4; ++c) {
      gload16(Ag + (size_t)(c * 32) * 256 + kc * 64 + sc_us, &As[(c * 32 + wave * 8) * 64]);
      gload16(Bg + (size_t)(c * 32) * 256 + kc * 64 + sc_us, &Bs[(c * 32 + wave * 8) * 64]);
    }
    __syncthreads();
#pragma unroll
    for (int kk = 0; kk < 2; ++kk) {
      bf16x8 a[4], bw[4];
#pragma unroll
      for (int i = 0; i < 4; ++i) {
        int r = wr * 64 + i * 16 + (lane & 15);
        a[i] = *(const bf16x8*)&As[r * 64 + ((kk * 32 + (lane >> 4) * 8) ^ ((r & 7) << 3))];
      }
#pragma unroll
      for (int j = 0; j < 4; ++j) {
        int r = wc * 64 + j * 16 + (lane & 15);
        bw[j] = *(const bf16x8*)&Bs[r * 64 + ((kk * 32 + (lane >> 4) * 8) ^ ((r & 7) << 3))];
      }
#pragma unroll
      for (int i = 0; i < 4; ++i)
#pragma unroll
        for (int j = 0; j < 4; ++j)
          acc[i][j] = __builtin_amdgcn_mfma_f32_16x16x32_bf16(a[i], bw[j], acc[i][j], 0, 0, 0);
    }
  }
  int o0 = ot * 128 + wr * 64;
  float bv[4][4];
#pragma unroll
  for (int i = 0; i < 4; ++i)
#pragma unroll
    for (int r = 0; r < 4; ++r) bv[i][r] = bias_g[o0 + i * 16 + (lane >> 4) * 4 + r];
  __syncthreads();
#pragma unroll
  for (int i = 0; i < 4; ++i)
#pragma unroll
    for (int j = 0; j < 4; ++j)
#pragma unroll
      for (int r = 0; r < 4; ++r) {
        int ol = wr * 64 + i * 16 + (lane >> 4) * 4 + r;
        int sl2 = wc * 64 + j * 16 + (lane & 15);
        sm.c[ol * 136 + sl2] = f2bf(acc[i][j][r] + bv[i][r]);
      }
  __syncthreads();
  uint16_t* outb = qkv + ((size_t)b * 1536 + ot * 128) * 4096 + st * 128;
  int rrow = t >> 4, rcol = (t & 15) * 8;
#pragma unroll
  for (int p = 0; p < 8; ++p) {
    int row = p * 16 + rrow;
    ushortx8 v = *(ushortx8*)&sm.c[row * 136 + rcol];
    *(ushortx8*)(outb + (size_t)row * 4096 + rcol) = v;
  }
}

// ---------------------------------------------------------------------------
// k_scales: scale[b][g][c16][s] = 1/max(sqrt(sum_h qkv[g*512+h*16+c16][s]^2), eps)
// grid (sc=32, g=2, NB); scaleB per-batch stride 524288 f32 (aliases Xt)
// ---------------------------------------------------------------------------
__global__ __launch_bounds__(256) void k_scales(const uint16_t* __restrict__ qkv,
                                                float* __restrict__ scaleB) {
  int t = threadIdx.x;
  int sc = blockIdx.x, g = blockIdx.y, b = blockIdx.z;
  const uint16_t* base = qkv + ((size_t)(b * 1536 + g * 512)) * 4096;
  float* sb = scaleB + (size_t)b * 524288 + (size_t)g * 65536;
  int c16 = t >> 4, so = t & 15;
  int s = sc * 128 + so * 8;
  float ss[8] = {};
  for (int h = 0; h < 32; ++h) {
    ushortx8 v = *(const ushortx8*)(base + ((size_t)(h * 16 + c16)) * 4096 + s);
#pragma unroll
    for (int j = 0; j < 8; ++j) { float f = bf2f(v[j]); ss[j] += f * f; }
  }
  floatx4 o0, o1;
#pragma unroll
  for (int j = 0; j < 4; ++j) o0[j] = 1.0f / fmaxf(sqrtf(ss[j]), 1e-12f);
#pragma unroll
  for (int j = 0; j < 4; ++j) o1[j] = 1.0f / fmaxf(sqrtf(ss[4 + j]), 1e-12f);
  *(floatx4*)(sb + c16 * 4096 + s) = o0;
  *(floatx4*)(sb + c16 * 4096 + s + 4) = o1;
}

// ---------------------------------------------------------------------------
// k_attn v4: per (b,h), 512 threads / 8 waves, 52.5KB LDS.
//  QK^T: BK=32, fused-scale register staging, SOFTWARE-PIPELINED: raw loads
//        for kc+1 issued before kc's MFMA cluster (T14). setprio on MFMA (T5).
//  softmax in-register (16-lane groups), unnormalized P -> Pb (XOR-swz).
//  PV: V [256][32] per (mc,half) via gload16; epilogue via pad-66 patches,
//      coalesced stores into OtT[D][s2] (aliases qkv q-region).
// grid (h=32, NB)
// ---------------------------------------------------------------------------
__global__ __launch_bounds__(512, 4) void k_attn(const uint16_t* __restrict__ qkv,
                                                 const float* __restrict__ scaleB,
                                                 uint16_t* OtAll) {
  __shared__ __align__(16) uint16_t stage[10240]; // QT[128][40]+KT[128][40]; V[256][32]; epi patches
  __shared__ __align__(16) uint16_t Pb[16384];    // P [128][128] (XOR-swizzled)
  __shared__ float rsum[128];
  int t = threadIdx.x, lane = t & 63, w = t >> 6;
  int h = blockIdx.x, b = blockIdx.y;
  const uint16_t* qg = qkv + ((size_t)(b * 1536) + h * 16) * 4096;
  const uint16_t* kg = qkv + ((size_t)(b * 1536) + 512 + h * 16) * 4096;
  const float* sq = scaleB + (size_t)b * 524288;
  const float* sk = sq + 65536;
  uint16_t* QT = stage;          // [128][40]
  uint16_t* KT = stage + 5120;   // [128][40]

  int sl = t & 127;   // l
  int sb8 = t >> 7;   // dd-octet 0..3

  // ---- S = Q^ * K^T (K=512 in 16 chunks of 32), fused scaling, pipelined ----
  f32x4 accs[8] = {};
  ushortx8 rq, rk;
  float sqv[8], skv[8];
  {
    const uint16_t* qrow = qg + sl;
    const uint16_t* krow = kg + sl;
    const float* sqr = sq + sl;
    const float* skr = sk + sl;
#pragma unroll
    for (int j = 0; j < 8; ++j) {
      int soff = (sb8 * 8 + j) * 128;
      rq[j] = qrow[soff]; rk[j] = krow[soff];
      sqv[j] = sqr[soff]; skv[j] = skr[soff];
    }
  }
  for (int kc = 0; kc < 16; ++kc) {
    // convert current raw -> scaled bf16
    ushortx8 oq, ok;
#pragma unroll
    for (int j = 0; j < 8; ++j) {
      oq[j] = f2bf(bf2f(rq[j]) * sqv[j]);
      ok[j] = f2bf(bf2f(rk[j]) * skv[j]);
    }
    __syncthreads();  // previous MFMA reads done
    int lidx = sl * 40 + sb8 * 8;
    *(ushortx8*)&QT[lidx] = oq;
    *(ushortx8*)&KT[lidx] = ok;
    __syncthreads();
    // prefetch kc+1 raw data (latency hides under MFMA + barrier waits)
    if (kc < 15) {
      const uint16_t* qrow = qg + (size_t)(kc + 1) * 4096 + sl;
      const uint16_t* krow = kg + (size_t)(kc + 1) * 4096 + sl;
      const float* sqr = sq + (kc + 1) * 4096 + sl;
      const float* skr = sk + (kc + 1) * 4096 + sl;
#pragma unroll
      for (int j = 0; j < 8; ++j) {
        int soff = (sb8 * 8 + j) * 128;
        rq[j] = qrow[soff]; rk[j] = krow[soff];
        sqv[j] = sqr[soff]; skv[j] = skr[soff];
      }
    }
    int ra = w * 16 + (lane & 15);
    bf16x8 aq = *(const bf16x8*)&QT[ra * 40 + (lane >> 4) * 8];
    __builtin_amdgcn_s_setprio(1);
#pragma unroll
    for (int mf = 0; mf < 8; ++mf) {
      int rm = mf * 16 + (lane & 15);
      bf16x8 bk = *(const bf16x8*)&KT[rm * 40 + (lane >> 4) * 8];
      accs[mf] = __builtin_amdgcn_mfma_f32_16x16x32_bf16(aq, bk, accs[mf], 0, 0, 0);
    }
    __builtin_amdgcn_s_setprio(0);
  }

  // ---- softmax (row spread over 16-lane group), P unnormalized ----
#pragma unroll
  for (int r = 0; r < 4; ++r) {
    float mx = accs[0][r];
#pragma unroll
    for (int mf = 1; mf < 8; ++mf) mx = fmaxf(mx, accs[mf][r]);
    mx = redmax16(mx);
    float sum = 0.f;
#pragma unroll
    for (int mf = 0; mf < 8; ++mf) {
      float e = __expf(accs[mf][r] - mx);
      accs[mf][r] = e;
      sum += e;
    }
    sum = redsum16(sum);
    int l = w * 16 + (lane >> 4) * 4 + r;
    if ((lane & 15) == 0) rsum[l] = 1.0f / sum;
#pragma unroll
    for (int mf = 0; mf < 8; ++mf) {
      int m = mf * 16 + (lane & 15);
      Pb[l * 128 + (m ^ ((l & 7) << 3))] = f2bf(accs[mf][r]);
    }
  }
  __syncthreads();

  // ---- out = V * P^T ----
  const uint16_t* vg = qkv + ((size_t)(b * 1536) + 1024 + h * 16) * 4096;
  uint16_t* OtT = OtAll + (size_t)b * 6291456;  // [512][4096] q-region of batch b
  uint16_t* Vt = stage;                          // [256][32]
  int vrow = lane >> 2;
  int vcol_us = ((((lane & 3) * 16) ^ ((vrow & 3) << 4)) >> 1);

#pragma unroll
  for (int lc = 0; lc < 2; ++lc) {
    f32x4 acco[2][2][4] = {};
    for (int mc = 0; mc < 4; ++mc) {
      bf16x8 bp[4];
#pragma unroll
      for (int lf = 0; lf < 4; ++lf) {
        int l = lc * 64 + lf * 16 + (lane & 15);
        bp[lf] = *(const bf16x8*)&Pb[l * 128 + ((mc * 32 + (lane >> 4) * 8) ^ ((l & 7) << 3))];
      }
#pragma unroll
      for (int half = 0; half < 2; ++half) {
        __syncthreads();
#pragma unroll
        for (int c = 0; c < 2; ++c) {
          int d = half * 256 + w * 32 + c * 16 + vrow;
          gload16(vg + (size_t)(d >> 5) * 4096 + (d & 31) * 128 + mc * 32 + vcol_us,
                  &Vt[(w * 32 + c * 16) * 32]);
        }
        __syncthreads();
        __builtin_amdgcn_s_setprio(1);
#pragma unroll
        for (int df = 0; df < 2; ++df) {
          int rv = w * 32 + df * 16 + (lane & 15);
          bf16x8 av = *(const bf16x8*)&Vt[rv * 32 + (((lane >> 4) * 8) ^ ((rv & 3) << 3))];
#pragma unroll
          for (int lf = 0; lf < 4; ++lf)
            acco[half][df][lf] =
                __builtin_amdgcn_mfma_f32_16x16x32_bf16(av, bp[lf], acco[half][df][lf], 0, 0, 0);
        }
        __builtin_amdgcn_s_setprio(0);
      }
    }
    float scl[4];
#pragma unroll
    for (int lf = 0; lf < 4; ++lf) scl[lf] = rsum[lc * 64 + lf * 16 + (lane & 15)];

    __syncthreads();  // all MFMA reads of Vt done; stage region free for patches
    uint16_t* patch = stage + w * 1056;  // [16][66] per wave
#pragma unroll
    for (int half = 0; half < 2; ++half) {
      uint16_t* obase = OtT + (size_t)(h * 16 + half * 8 + w) * 4096;
#pragma unroll
      for (int df = 0; df < 2; ++df) {
#pragma unroll
        for (int r = 0; r < 4; ++r) {
          int dlocal = (lane >> 4) * 4 + r;
#pragma unroll
          for (int lf = 0; lf < 4; ++lf)
            patch[dlocal * 66 + lf * 16 + (lane & 15)] = f2bf(acco[half][df][lf][r] * scl[lf]);
        }
        asm volatile("s_waitcnt lgkmcnt(0)" ::: "memory");
        __builtin_amdgcn_sched_barrier(0);
        int dl = lane >> 2, l8 = (lane & 3) * 16;
        uint16_t tmp[16];
#pragma unroll
        for (int e = 0; e < 8; ++e)
          *(uint32_t*)&tmp[e * 2] = *(const uint32_t*)&patch[dl * 66 + l8 + e * 2];
        uint16_t* gp = obase + (df * 16 + dl) * 128 + lc * 64 + l8;
        *(ushortx8*)gp = *(ushortx8*)&tmp[0];
        *(ushortx8*)(gp + 8) = *(ushortx8*)&tmp[8];
        asm volatile("s_waitcnt lgkmcnt(0)" ::: "memory");  // patch reads done before next overwrite
        __builtin_amdgcn_sched_barrier(0);
      }
    }
  }
}

// ---------------------------------------------------------------------------
// final[b][c][s] = sum_D Wp[c][D]*OtT[D][s] + bias[c]   (f32 out)
// B staged by 8-element gather from OtT (stride 4096); grid (st=32, ct=2, NB)
// ---------------------------------------------------------------------------
__global__ __launch_bounds__(256) void k_proj_gemm(const uint16_t* __restrict__ Wp,
                                                   const uint16_t* __restrict__ OtAll,
                                                   const float* __restrict__ bias_g,
                                                   float* __restrict__ outp) {
  __shared__ __align__(16) uint16_t As[128 * 64];
  __shared__ __align__(16) uint16_t Bs[128 * 64];
  int t = threadIdx.x, lane = t & 63, wave = t >> 6;
  int st = blockIdx.x, ct = blockIdx.y, b = blockIdx.z;
  int wr = wave >> 1, wc = wave & 1;
  f32x4 acc[4][4] = {};
  int srow = lane >> 3;
  int sc_us = ((((lane & 7) * 16) ^ ((srow & 7) << 4)) >> 1);
  const uint16_t* Ag = Wp + (size_t)(ct * 128 + wave * 8 + srow) * 512;
  const uint16_t* Ob = OtAll + (size_t)b * 6291456;

  for (int kc = 0; kc < 8; ++kc) {
    __syncthreads();
#pragma unroll
    for (int c = 0; c < 4; ++c)
      gload16(Ag + (size_t)(c * 32) * 512 + kc * 64 + sc_us, &As[(c * 32 + wave * 8) * 64]);
#pragma unroll
    for (int k = 0; k < 4; ++k) {
      int cid = k * 256 + t;
      int row = cid & 127, dd8 = cid >> 7;
      const uint16_t* src = Ob + (size_t)(kc * 64 + dd8 * 8) * 4096 + st * 128 + row;
      ushortx8 o;
#pragma unroll
      for (int j = 0; j < 8; ++j) o[j] = src[(size_t)j * 4096];
      *(ushortx8*)&Bs[row * 64 + ((dd8 * 8) ^ ((row & 7) << 3))] = o;
    }
    __syncthreads();
#pragma unroll
    for (int kk = 0; kk < 2; ++kk) {
      bf16x8 a[4], bw[4];
#pragma unroll
      for (int i = 0; i < 4; ++i) {
        int r = wr * 64 + i * 16 + (lane & 15);
        a[i] = *(const bf16x8*)&As[r * 64 + ((kk * 32 + (lane >> 4) * 8) ^ ((r & 7) << 3))];
      }
#pragma unroll
      for (int j = 0; j < 4; ++j) {
        int r = wc * 64 + j * 16 + (lane & 15);
        bw[j] = *(const bf16x8*)&Bs[r * 64 + ((kk * 32 + (lane >> 4) * 8) ^ ((r & 7) << 3))];
      }
#pragma unroll
      for (int i = 0; i < 4; ++i)
#pragma unroll
        for (int j = 0; j < 4; ++j)
          acc[i][j] = __builtin_amdgcn_mfma_f32_16x16x32_bf16(a[i], bw[j], acc[i][j], 0, 0, 0);
    }
  }
  int c0 = ct * 128 + wr * 64, s0 = st * 128 + wc * 64;
  float bv[4][4];
#pragma unroll
  for (int i = 0; i < 4; ++i)
#pragma unroll
    for (int r = 0; r < 4; ++r) bv[i][r] = bias_g[c0 + i * 16 + (lane >> 4) * 4 + r];
#pragma unroll
  for (int i = 0; i < 4; ++i)
#pragma unroll
    for (int j = 0; j < 4; ++j)
#pragma unroll
      for (int r = 0; r < 4; ++r) {
        int c = c0 + i * 16 + (lane >> 4) * 4 + r;
        int s = s0 + j * 16 + (lane & 15);
        outp[((size_t)b * 256 + c) * 4096 + s] = acc[i][j][r] + bv[i][r];
      }
}

// ---------------------------------------------------------------------------
extern "C" void kernel_launch(void* const* d_in, const int* in_sizes, int n_in,
                              void* d_out, int out_size, void* d_ws, size_t ws_size,
                              hipStream_t stream) {
  const float* X      = (const float*)d_in[0];
  const float* qkv_w  = (const float*)d_in[1];
  const float* qkv_b  = (const float*)d_in[2];
  const float* proj_w = (const float*)d_in[3];
  const float* proj_b = (const float*)d_in[4];
  float* outp = (float*)d_out;

  const size_t SZ_XT  = 2097152;   // Xt; scaleB aliases here
  const size_t SZ_QKV = 12582912;  // qkv; q region doubles as OtT[512][4096]
  const size_t SZ_W   = 786432 + 262144;

  int NB = 0;
  const int cand[6] = {32, 16, 8, 4, 2, 1};
  for (int ci = 0; ci < 6; ++ci) {
    size_t need = SZ_W + (size_t)cand[ci] * (SZ_XT + SZ_QKV);
    if (need <= ws_size) { NB = cand[ci]; break; }
  }
  if (NB == 0) return;

  char* ws = (char*)d_ws;
  uint16_t* Wqb  = (uint16_t*)(ws);
  uint16_t* Wpb  = (uint16_t*)(ws + 786432);
  char*     gbuf = ws + SZ_W;
  uint16_t* Xt   = (uint16_t*)(gbuf);
  uint16_t* qkvb = (uint16_t*)(gbuf + (size_t)NB * SZ_XT);
  float*    scaleB = (float*)Xt;   // per-batch stride 524288 f32

  k_cvt_bf16<<<dim3(384), 256, 0, stream>>>(qkv_w, Wqb, 1536 * 256);
  k_cvt_bf16<<<dim3(128), 256, 0, stream>>>(proj_w, Wpb, 256 * 512);

  for (int b0 = 0; b0 < 32; b0 += NB) {
    const float* Xg   = X + (size_t)b0 * 256 * 4096;
    float*       outg = outp + (size_t)b0 * 256 * 4096;
    k_transpose_x<<<dim3(64, 4, NB), 256, 0, stream>>>(Xg, Xt);
    k_qkv_gemm<<<dim3(12, 32, NB), 256, 0, stream>>>(Wqb, Xt, qkv_b, qkvb);
    k_scales<<<dim3(32, 2, NB), 256, 0, stream>>>(qkvb, scaleB);
    k_attn<<<dim3(32, NB), 512, 0, stream>>>(qkvb, scaleB, qkvb /*OtT*/);
    k_proj_gemm<<<dim3(32, 2, NB), 256, 0, stream>>>(Wpb, qkvb /*OtT*/, proj_b, outg);
  }
}

// Round 9
// 567.379 us; speedup vs baseline: 1.1750x; 1.0143x over previous
//
#include <hip/hip_runtime.h>
#include <stdint.h>

// ============================================================================
// RelativeSelfAttention on MI355X (gfx950)
// B=32, C=256, S=4096, heads=32, "HEAD_DIM"=512, L=128
// per (b,h): Q/K/V = qkv[b, g*512+h*16 .. +16, :] viewed as [d=512][l=128],
//   d = c16*32 + s_hi, s = s_hi*128 + l.
// Output reshape: Ot[s2][D], D = h*16 + (d>>5), s2 = (d&31)*128 + l.
// R9: qkv_gemm gets XCD-bijective block swizzle (T1): the 12 ot-blocks that
//     share an Xt B-tile now run consecutively ON THE SAME XCD (they were
//     round-robined across 8 XCDs -> 4x HBM over-fetch, FETCH=264MB vs 65).
// ============================================================================

typedef float     f32x4   __attribute__((ext_vector_type(4)));
typedef short     bf16x8  __attribute__((ext_vector_type(8)));
typedef float     floatx4 __attribute__((ext_vector_type(4)));
typedef uint16_t  ushortx8 __attribute__((ext_vector_type(8)));
typedef uint16_t  ushortx4 __attribute__((ext_vector_type(4)));

#define DEVI static __device__ __forceinline__

DEVI float bf2f(uint16_t u) { union { uint32_t i; float f; } x; x.i = ((uint32_t)u) << 16; return x.f; }
DEVI uint16_t f2bf(float f) {
  union { float f; uint32_t i; } x; x.f = f;
  uint32_t r = x.i + 0x7fff + ((x.i >> 16) & 1);
  return (uint16_t)(r >> 16);
}

DEVI void gload16(const void* g, void* l) {
  __builtin_amdgcn_global_load_lds((const __attribute__((address_space(1))) void*)g,
                                   (__attribute__((address_space(3))) void*)l, 16, 0, 0);
}

DEVI float redmax16(float v) {
  v = fmaxf(v, __shfl_xor(v, 1)); v = fmaxf(v, __shfl_xor(v, 2));
  v = fmaxf(v, __shfl_xor(v, 4)); v = fmaxf(v, __shfl_xor(v, 8));
  return v;
}
DEVI float redsum16(float v) {
  v += __shfl_xor(v, 1); v += __shfl_xor(v, 2);
  v += __shfl_xor(v, 4); v += __shfl_xor(v, 8);
  return v;
}

// ---------------------------------------------------------------------------
// X[b][c][s] f32  ->  Xt[b][s][c] bf16   (LDS 64x64 padded transpose)
// grid (st=64, ct=4, NB)
// ---------------------------------------------------------------------------
__global__ __launch_bounds__(256) void k_transpose_x(const float* __restrict__ X,
                                                     uint16_t* __restrict__ Xt) {
  __shared__ float tile[64][65];
  int t = threadIdx.x;
  int st = blockIdx.x, ct = blockIdx.y, b = blockIdx.z;
  int row = t >> 2, cq = t & 3;
  const float* src = X + ((size_t)(b * 256 + ct * 64 + row)) * 4096 + st * 64 + cq * 16;
#pragma unroll
  for (int k = 0; k < 4; ++k) {
    floatx4 v = *(const floatx4*)(src + k * 4);
    tile[row][cq * 16 + k * 4 + 0] = v[0];
    tile[row][cq * 16 + k * 4 + 1] = v[1];
    tile[row][cq * 16 + k * 4 + 2] = v[2];
    tile[row][cq * 16 + k * 4 + 3] = v[3];
  }
  __syncthreads();
  int srow = t >> 2, oq = t & 3;
  ushortx8 o0, o1;
#pragma unroll
  for (int k = 0; k < 8; ++k) o0[k] = f2bf(tile[oq * 16 + k][srow]);
#pragma unroll
  for (int k = 0; k < 8; ++k) o1[k] = f2bf(tile[oq * 16 + 8 + k][srow]);
  uint16_t* dst = Xt + ((size_t)(b * 4096 + st * 64 + srow)) * 256 + ct * 64 + oq * 16;
  *(ushortx8*)dst = o0;
  *(ushortx8*)(dst + 8) = o1;
}

// ---------------------------------------------------------------------------
// flat f32 -> bf16 (weights)
// ---------------------------------------------------------------------------
__global__ __launch_bounds__(256) void k_cvt_bf16(const float* __restrict__ src,
                                                  uint16_t* __restrict__ dst, int n) {
  int i = (blockIdx.x * 256 + threadIdx.x) * 4;
  if (i >= n) return;
  floatx4 v = *(const floatx4*)(src + i);
  ushortx4 o;
  o[0] = f2bf(v[0]); o[1] = f2bf(v[1]); o[2] = f2bf(v[2]); o[3] = f2bf(v[3]);
  *(ushortx4*)(dst + i) = o;
}

// ---------------------------------------------------------------------------
// qkv[b][o][s] = sum_c W[o][c]*Xt[b][s][c] + bias[o]   (bf16 out)
// 1D grid nwg=384*NB, XCD-bijective swizzle; decode work -> (ot,st,b) with
// ot fastest so the 12 ot-blocks of one B-tile are adjacent on ONE XCD.
// C-write via LDS repack (coalesced 16B/lane).
// ---------------------------------------------------------------------------
__global__ __launch_bounds__(256) void k_qkv_gemm(const uint16_t* __restrict__ W,
                                                  const uint16_t* __restrict__ Xt,
                                                  const float* __restrict__ bias_g,
                                                  uint16_t* __restrict__ qkv,
                                                  int nwg) {
  __shared__ __align__(16) union {
    uint16_t ab[2][128 * 64];   // As, Bs
    uint16_t c[128 * 136];      // C repack (padded stride)
  } sm;
  uint16_t* As = sm.ab[0];
  uint16_t* Bs = sm.ab[1];
  int t = threadIdx.x, lane = t & 63, wave = t >> 6;
  // XCD-bijective swizzle (nwg divisible by 8): contiguous chunk per XCD
  int orig = blockIdx.x;
  int wkid = (orig & 7) * (nwg >> 3) + (orig >> 3);
  int ot = wkid % 12;
  int r0 = wkid / 12;
  int st = r0 & 31, b = r0 >> 5;
  int wr = wave >> 1, wc = wave & 1;
  f32x4 acc[4][4] = {};
  int srow = lane >> 3;
  int sc_us = ((((lane & 7) * 16) ^ ((srow & 7) << 4)) >> 1);
  const uint16_t* Ag = W + (size_t)(ot * 128 + wave * 8 + srow) * 256;
  const uint16_t* Bg = Xt + ((size_t)(b * 4096 + st * 128 + wave * 8 + srow)) * 256;

  for (int kc = 0; kc < 4; ++kc) {
    __syncthreads();
#pragma unroll
    for (int c = 0; c < 4; ++c) {
      gload16(Ag + (size_t)(c * 32) * 256 + kc * 64 + sc_us, &As[(c * 32 + wave * 8) * 64]);
      gload16(Bg + (size_t)(c * 32) * 256 + kc * 64 + sc_us, &Bs[(c * 32 + wave * 8) * 64]);
    }
    __syncthreads();
#pragma unroll
    for (int kk = 0; kk < 2; ++kk) {
      bf16x8 a[4], bw[4];
#pragma unroll
      for (int i = 0; i < 4; ++i) {
        int r = wr * 64 + i * 16 + (lane & 15);
        a[i] = *(const bf16x8*)&As[r * 64 + ((kk * 32 + (lane >> 4) * 8) ^ ((r & 7) << 3))];
      }
#pragma unroll
      for (int j = 0; j < 4; ++j) {
        int r = wc * 64 + j * 16 + (lane & 15);
        bw[j] = *(const bf16x8*)&Bs[r * 64 + ((kk * 32 + (lane >> 4) * 8) ^ ((r & 7) << 3))];
      }
#pragma unroll
      for (int i = 0; i < 4; ++i)
#pragma unroll
        for (int j = 0; j < 4; ++j)
          acc[i][j] = __builtin_amdgcn_mfma_f32_16x16x32_bf16(a[i], bw[j], acc[i][j], 0, 0, 0);
    }
  }
  int o0 = ot * 128 + wr * 64;
  float bv[4][4];
#pragma unroll
  for (int i = 0; i < 4; ++i)
#pragma unroll
    for (int r = 0; r < 4; ++r) bv[i][r] = bias_g[o0 + i * 16 + (lane >> 4) * 4 + r];
  __syncthreads();
#pragma unroll
  for (int i = 0; i < 4; ++i)
#pragma unroll
    for (int j = 0; j < 4; ++j)
#pragma unroll
      for (int r = 0; r < 4; ++r) {
        int ol = wr * 64 + i * 16 + (lane >> 4) * 4 + r;
        int sl2 = wc * 64 + j * 16 + (lane & 15);
        sm.c[ol * 136 + sl2] = f2bf(acc[i][j][r] + bv[i][r]);
      }
  __syncthreads();
  uint16_t* outb = qkv + ((size_t)b * 1536 + ot * 128) * 4096 + st * 128;
  int rrow = t >> 4, rcol = (t & 15) * 8;
#pragma unroll
  for (int p = 0; p < 8; ++p) {
    int row = p * 16 + rrow;
    ushortx8 v = *(ushortx8*)&sm.c[row * 136 + rcol];
    *(ushortx8*)(outb + (size_t)row * 4096 + rcol) = v;
  }
}

// ---------------------------------------------------------------------------
// k_scales: scale[b][g][c16][s] = 1/max(sqrt(sum_h qkv[g*512+h*16+c16][s]^2), eps)
// grid (sc=32, g=2, NB); scaleB per-batch stride 524288 f32 (aliases Xt)
// ---------------------------------------------------------------------------
__global__ __launch_bounds__(256) void k_scales(const uint16_t* __restrict__ qkv,
                                                float* __restrict__ scaleB) {
  int t = threadIdx.x;
  int sc = blockIdx.x, g = blockIdx.y, b = blockIdx.z;
  const uint16_t* base = qkv + ((size_t)(b * 1536 + g * 512)) * 4096;
  float* sb = scaleB + (size_t)b * 524288 + (size_t)g * 65536;
  int c16 = t >> 4, so = t & 15;
  int s = sc * 128 + so * 8;
  float ss[8] = {};
  for (int h = 0; h < 32; ++h) {
    ushortx8 v = *(const ushortx8*)(base + ((size_t)(h * 16 + c16)) * 4096 + s);
#pragma unroll
    for (int j = 0; j < 8; ++j) { float f = bf2f(v[j]); ss[j] += f * f; }
  }
  floatx4 o0, o1;
#pragma unroll
  for (int j = 0; j < 4; ++j) o0[j] = 1.0f / fmaxf(sqrtf(ss[j]), 1e-12f);
#pragma unroll
  for (int j = 0; j < 4; ++j) o1[j] = 1.0f / fmaxf(sqrtf(ss[4 + j]), 1e-12f);
  *(floatx4*)(sb + c16 * 4096 + s) = o0;
  *(floatx4*)(sb + c16 * 4096 + s + 4) = o1;
}

// ---------------------------------------------------------------------------
// k_attn v4: per (b,h), 512 threads / 8 waves, 52.5KB LDS.
//  QK^T: BK=32, fused-scale register staging, pipelined prefetch (T14),
//        setprio on MFMA (T5).
//  softmax in-register (16-lane groups), unnormalized P -> Pb (XOR-swz).
//  PV: V [256][32] per (mc,half) via gload16; epilogue via pad-66 patches,
//      coalesced stores into OtT[D][s2] (aliases qkv q-region).
// grid (h=32, NB)
// ---------------------------------------------------------------------------
__global__ __launch_bounds__(512, 4) void k_attn(const uint16_t* __restrict__ qkv,
                                                 const float* __restrict__ scaleB,
                                                 uint16_t* OtAll) {
  __shared__ __align__(16) uint16_t stage[10240]; // QT[128][40]+KT[128][40]; V[256][32]; epi patches
  __shared__ __align__(16) uint16_t Pb[16384];    // P [128][128] (XOR-swizzled)
  __shared__ float rsum[128];
  int t = threadIdx.x, lane = t & 63, w = t >> 6;
  int h = blockIdx.x, b = blockIdx.y;
  const uint16_t* qg = qkv + ((size_t)(b * 1536) + h * 16) * 4096;
  const uint16_t* kg = qkv + ((size_t)(b * 1536) + 512 + h * 16) * 4096;
  const float* sq = scaleB + (size_t)b * 524288;
  const float* sk = sq + 65536;
  uint16_t* QT = stage;          // [128][40]
  uint16_t* KT = stage + 5120;   // [128][40]

  int sl = t & 127;   // l
  int sb8 = t >> 7;   // dd-octet 0..3

  // ---- S = Q^ * K^T (K=512 in 16 chunks of 32), fused scaling, pipelined ----
  f32x4 accs[8] = {};
  ushortx8 rq, rk;
  float sqv[8], skv[8];
  {
    const uint16_t* qrow = qg + sl;
    const uint16_t* krow = kg + sl;
    const float* sqr = sq + sl;
    const float* skr = sk + sl;
#pragma unroll
    for (int j = 0; j < 8; ++j) {
      int soff = (sb8 * 8 + j) * 128;
      rq[j] = qrow[soff]; rk[j] = krow[soff];
      sqv[j] = sqr[soff]; skv[j] = skr[soff];
    }
  }
  for (int kc = 0; kc < 16; ++kc) {
    ushortx8 oq, ok;
#pragma unroll
    for (int j = 0; j < 8; ++j) {
      oq[j] = f2bf(bf2f(rq[j]) * sqv[j]);
      ok[j] = f2bf(bf2f(rk[j]) * skv[j]);
    }
    __syncthreads();  // previous MFMA reads done
    int lidx = sl * 40 + sb8 * 8;
    *(ushortx8*)&QT[lidx] = oq;
    *(ushortx8*)&KT[lidx] = ok;
    __syncthreads();
    if (kc < 15) {
      const uint16_t* qrow = qg + (size_t)(kc + 1) * 4096 + sl;
      const uint16_t* krow = kg + (size_t)(kc + 1) * 4096 + sl;
      const float* sqr = sq + (kc + 1) * 4096 + sl;
      const float* skr = sk + (kc + 1) * 4096 + sl;
#pragma unroll
      for (int j = 0; j < 8; ++j) {
        int soff = (sb8 * 8 + j) * 128;
        rq[j] = qrow[soff]; rk[j] = krow[soff];
        sqv[j] = sqr[soff]; skv[j] = skr[soff];
      }
    }
    int ra = w * 16 + (lane & 15);
    bf16x8 aq = *(const bf16x8*)&QT[ra * 40 + (lane >> 4) * 8];
    __builtin_amdgcn_s_setprio(1);
#pragma unroll
    for (int mf = 0; mf < 8; ++mf) {
      int rm = mf * 16 + (lane & 15);
      bf16x8 bk = *(const bf16x8*)&KT[rm * 40 + (lane >> 4) * 8];
      accs[mf] = __builtin_amdgcn_mfma_f32_16x16x32_bf16(aq, bk, accs[mf], 0, 0, 0);
    }
    __builtin_amdgcn_s_setprio(0);
  }

  // ---- softmax (row spread over 16-lane group), P unnormalized ----
#pragma unroll
  for (int r = 0; r < 4; ++r) {
    float mx = accs[0][r];
#pragma unroll
    for (int mf = 1; mf < 8; ++mf) mx = fmaxf(mx, accs[mf][r]);
    mx = redmax16(mx);
    float sum = 0.f;
#pragma unroll
    for (int mf = 0; mf < 8; ++mf) {
      float e = __expf(accs[mf][r] - mx);
      accs[mf][r] = e;
      sum += e;
    }
    sum = redsum16(sum);
    int l = w * 16 + (lane >> 4) * 4 + r;
    if ((lane & 15) == 0) rsum[l] = 1.0f / sum;
#pragma unroll
    for (int mf = 0; mf < 8; ++mf) {
      int m = mf * 16 + (lane & 15);
      Pb[l * 128 + (m ^ ((l & 7) << 3))] = f2bf(accs[mf][r]);
    }
  }
  __syncthreads();

  // ---- out = V * P^T ----
  const uint16_t* vg = qkv + ((size_t)(b * 1536) + 1024 + h * 16) * 4096;
  uint16_t* OtT = OtAll + (size_t)b * 6291456;  // [512][4096] q-region of batch b
  uint16_t* Vt = stage;                          // [256][32]
  int vrow = lane >> 2;
  int vcol_us = ((((lane & 3) * 16) ^ ((vrow & 3) << 4)) >> 1);

#pragma unroll
  for (int lc = 0; lc < 2; ++lc) {
    f32x4 acco[2][2][4] = {};
    for (int mc = 0; mc < 4; ++mc) {
      bf16x8 bp[4];
#pragma unroll
      for (int lf = 0; lf < 4; ++lf) {
        int l = lc * 64 + lf * 16 + (lane & 15);
        bp[lf] = *(const bf16x8*)&Pb[l * 128 + ((mc * 32 + (lane >> 4) * 8) ^ ((l & 7) << 3))];
      }
#pragma unroll
      for (int half = 0; half < 2; ++half) {
        __syncthreads();
#pragma unroll
        for (int c = 0; c < 2; ++c) {
          int d = half * 256 + w * 32 + c * 16 + vrow;
          gload16(vg + (size_t)(d >> 5) * 4096 + (d & 31) * 128 + mc * 32 + vcol_us,
                  &Vt[(w * 32 + c * 16) * 32]);
        }
        __syncthreads();
        __builtin_amdgcn_s_setprio(1);
#pragma unroll
        for (int df = 0; df < 2; ++df) {
          int rv = w * 32 + df * 16 + (lane & 15);
          bf16x8 av = *(const bf16x8*)&Vt[rv * 32 + (((lane >> 4) * 8) ^ ((rv & 3) << 3))];
#pragma unroll
          for (int lf = 0; lf < 4; ++lf)
            acco[half][df][lf] =
                __builtin_amdgcn_mfma_f32_16x16x32_bf16(av, bp[lf], acco[half][df][lf], 0, 0, 0);
        }
        __builtin_amdgcn_s_setprio(0);
      }
    }
    float scl[4];
#pragma unroll
    for (int lf = 0; lf < 4; ++lf) scl[lf] = rsum[lc * 64 + lf * 16 + (lane & 15)];

    __syncthreads();  // all MFMA reads of Vt done; stage region free for patches
    uint16_t* patch = stage + w * 1056;  // [16][66] per wave
#pragma unroll
    for (int half = 0; half < 2; ++half) {
      uint16_t* obase = OtT + (size_t)(h * 16 + half * 8 + w) * 4096;
#pragma unroll
      for (int df = 0; df < 2; ++df) {
#pragma unroll
        for (int r = 0; r < 4; ++r) {
          int dlocal = (lane >> 4) * 4 + r;
#pragma unroll
          for (int lf = 0; lf < 4; ++lf)
            patch[dlocal * 66 + lf * 16 + (lane & 15)] = f2bf(acco[half][df][lf][r] * scl[lf]);
        }
        asm volatile("s_waitcnt lgkmcnt(0)" ::: "memory");
        __builtin_amdgcn_sched_barrier(0);
        int dl = lane >> 2, l8 = (lane & 3) * 16;
        uint16_t tmp[16];
#pragma unroll
        for (int e = 0; e < 8; ++e)
          *(uint32_t*)&tmp[e * 2] = *(const uint32_t*)&patch[dl * 66 + l8 + e * 2];
        uint16_t* gp = obase + (df * 16 + dl) * 128 + lc * 64 + l8;
        *(ushortx8*)gp = *(ushortx8*)&tmp[0];
        *(ushortx8*)(gp + 8) = *(ushortx8*)&tmp[8];
        asm volatile("s_waitcnt lgkmcnt(0)" ::: "memory");  // patch reads done before next overwrite
        __builtin_amdgcn_sched_barrier(0);
      }
    }
  }
}

// ---------------------------------------------------------------------------
// final[b][c][s] = sum_D Wp[c][D]*OtT[D][s] + bias[c]   (f32 out)
// B staged by 8-element gather from OtT (stride 4096); grid (st=32, ct=2, NB)
// ---------------------------------------------------------------------------
__global__ __launch_bounds__(256) void k_proj_gemm(const uint16_t* __restrict__ Wp,
                                                   const uint16_t* __restrict__ OtAll,
                                                   const float* __restrict__ bias_g,
                                                   float* __restrict__ outp) {
  __shared__ __align__(16) uint16_t As[128 * 64];
  __shared__ __align__(16) uint16_t Bs[128 * 64];
  int t = threadIdx.x, lane = t & 63, wave = t >> 6;
  int st = blockIdx.x, ct = blockIdx.y, b = blockIdx.z;
  int wr = wave >> 1, wc = wave & 1;
  f32x4 acc[4][4] = {};
  int srow = lane >> 3;
  int sc_us = ((((lane & 7) * 16) ^ ((srow & 7) << 4)) >> 1);
  const uint16_t* Ag = Wp + (size_t)(ct * 128 + wave * 8 + srow) * 512;
  const uint16_t* Ob = OtAll + (size_t)b * 6291456;

  for (int kc = 0; kc < 8; ++kc) {
    __syncthreads();
#pragma unroll
    for (int c = 0; c < 4; ++c)
      gload16(Ag + (size_t)(c * 32) * 512 + kc * 64 + sc_us, &As[(c * 32 + wave * 8) * 64]);
#pragma unroll
    for (int k = 0; k < 4; ++k) {
      int cid = k * 256 + t;
      int row = cid & 127, dd8 = cid >> 7;
      const uint16_t* src = Ob + (size_t)(kc * 64 + dd8 * 8) * 4096 + st * 128 + row;
      ushortx8 o;
#pragma unroll
      for (int j = 0; j < 8; ++j) o[j] = src[(size_t)j * 4096];
      *(ushortx8*)&Bs[row * 64 + ((dd8 * 8) ^ ((row & 7) << 3))] = o;
    }
    __syncthreads();
#pragma unroll
    for (int kk = 0; kk < 2; ++kk) {
      bf16x8 a[4], bw[4];
#pragma unroll
      for (int i = 0; i < 4; ++i) {
        int r = wr * 64 + i * 16 + (lane & 15);
        a[i] = *(const bf16x8*)&As[r * 64 + ((kk * 32 + (lane >> 4) * 8) ^ ((r & 7) << 3))];
      }
#pragma unroll
      for (int j = 0; j < 4; ++j) {
        int r = wc * 64 + j * 16 + (lane & 15);
        bw[j] = *(const bf16x8*)&Bs[r * 64 + ((kk * 32 + (lane >> 4) * 8) ^ ((r & 7) << 3))];
      }
#pragma unroll
      for (int i = 0; i < 4; ++i)
#pragma unroll
        for (int j = 0; j < 4; ++j)
          acc[i][j] = __builtin_amdgcn_mfma_f32_16x16x32_bf16(a[i], bw[j], acc[i][j], 0, 0, 0);
    }
  }
  int c0 = ct * 128 + wr * 64, s0 = st * 128 + wc * 64;
  float bv[4][4];
#pragma unroll
  for (int i = 0; i < 4; ++i)
#pragma unroll
    for (int r = 0; r < 4; ++r) bv[i][r] = bias_g[c0 + i * 16 + (lane >> 4) * 4 + r];
#pragma unroll
  for (int i = 0; i < 4; ++i)
#pragma unroll
    for (int j = 0; j < 4; ++j)
#pragma unroll
      for (int r = 0; r < 4; ++r) {
        int c = c0 + i * 16 + (lane >> 4) * 4 + r;
        int s = s0 + j * 16 + (lane & 15);
        outp[((size_t)b * 256 + c) * 4096 + s] = acc[i][j][r] + bv[i][r];
      }
}

// ---------------------------------------------------------------------------
extern "C" void kernel_launch(void* const* d_in, const int* in_sizes, int n_in,
                              void* d_out, int out_size, void* d_ws, size_t ws_size,
                              hipStream_t stream) {
  const float* X      = (const float*)d_in[0];
  const float* qkv_w  = (const float*)d_in[1];
  const float* qkv_b  = (const float*)d_in[2];
  const float* proj_w = (const float*)d_in[3];
  const float* proj_b = (const float*)d_in[4];
  float* outp = (float*)d_out;

  const size_t SZ_XT  = 2097152;   // Xt; scaleB aliases here
  const size_t SZ_QKV = 12582912;  // qkv; q region doubles as OtT[512][4096]
  const size_t SZ_W   = 786432 + 262144;

  int NB = 0;
  const int cand[6] = {32, 16, 8, 4, 2, 1};
  for (int ci = 0; ci < 6; ++ci) {
    size_t need = SZ_W + (size_t)cand[ci] * (SZ_XT + SZ_QKV);
    if (need <= ws_size) { NB = cand[ci]; break; }
  }
  if (NB == 0) return;

  char* ws = (char*)d_ws;
  uint16_t* Wqb  = (uint16_t*)(ws);
  uint16_t* Wpb  = (uint16_t*)(ws + 786432);
  char*     gbuf = ws + SZ_W;
  uint16_t* Xt   = (uint16_t*)(gbuf);
  uint16_t* qkvb = (uint16_t*)(gbuf + (size_t)NB * SZ_XT);
  float*    scaleB = (float*)Xt;   // per-batch stride 524288 f32

  k_cvt_bf16<<<dim3(384), 256, 0, stream>>>(qkv_w, Wqb, 1536 * 256);
  k_cvt_bf16<<<dim3(128), 256, 0, stream>>>(proj_w, Wpb, 256 * 512);

  for (int b0 = 0; b0 < 32; b0 += NB) {
    const float* Xg   = X + (size_t)b0 * 256 * 4096;
    float*       outg = outp + (size_t)b0 * 256 * 4096;
    int nwg = 384 * NB;
    k_transpose_x<<<dim3(64, 4, NB), 256, 0, stream>>>(Xg, Xt);
    k_qkv_gemm<<<dim3(nwg), 256, 0, stream>>>(Wqb, Xt, qkv_b, qkvb, nwg);
    k_scales<<<dim3(32, 2, NB), 256, 0, stream>>>(qkvb, scaleB);
    k_attn<<<dim3(32, NB), 512, 0, stream>>>(qkvb, scaleB, qkvb /*OtT*/);
    k_proj_gemm<<<dim3(32, 2, NB), 256, 0, stream>>>(Wpb, qkvb /*OtT*/, proj_b, outg);
  }
}